// Round 5
// baseline (248.420 us; speedup 1.0000x reference)
//
#include <hip/hip_runtime.h>

// ---------------------------------------------------------------------------
// MultiHeadAttention forward, MI355X/gfx950.
// B=2, S=2048, DIM=1024, H=16, d=64.  All GEMM-shaped compute on
// mfma_f32_16x16x32_bf16; softmax in fp32 (fixed-max, denominator via
// ones-MFMA over the rounded P -> self-normalizing).
//
// Pipeline (5 launches):
//   prep:       cast x->bf16; transpose+cast w_qkv, w_out  (fused)
//   gemm_qkv:   qkb[4096,2048] = {Q,K} thirds of xb @ wqkvt^T (Q pre-scaled
//               by 0.125*log2e so flash softmax is a bare v_exp_f32); V tiles
//               written transposed straight to vtg [B*H, 64, 2048] (d-major)
//   flash_attn: R5 block-level split-K. Grid 1024 = 8 xcd x 4 bh x 16 qb x
//               2 key-halves; each block = the proven R3 kernel (256 thr /
//               4 waves / 32 Q-rows per wave, in-register P via
//               permlane32/16 swaps, one barrier per key-iter) over HALF the
//               keys (16 iters). 4 blocks/CU -> 4 waves/SIMD from 4
//               independent barrier streams (R2/R3 showed lockstep blocks
//               leave MFMA+VALU additive at ~80%). Epilogue stores RAW
//               partials: O_g fp16, l_g fp32. No in-kernel combine.
//   combine:    aout = (O0+O1)/(l0+l1), elementwise, bf16 written IN-PLACE
//               over O1's buffer (per-thread same-address read->write).
//   gemm_n64:   d_out = aout @ woutt^T  (128x64 tiles, 2 blocks/CU)
//
// Workspace layout (unchanged 50 MB footprint; regions reused over time):
//   [ 0, 8) MB  xb (prep->gemm_qkv), then O0 fp16 (flash->combine)
//   [ 8,14) MB  wqkvt  (prep->gemm_qkv)
//   [14,14.5)   l0,l1 fp32 partial denominators (flash->combine)
//   [16,32) MB  qkb  [4096][2048] bf16  (gemm_qkv->flash)
//   [32,40) MB  vtg  [B*H][64][2048]    (gemm_qkv->flash)
//   [40,48) MB  O1 fp16 (flash->combine), then aout bf16 (combine->gemm_n64)
//   [48,50) MB  woutt                   (prep->gemm_n64)
// ---------------------------------------------------------------------------

typedef __bf16 bf16x8 __attribute__((ext_vector_type(8)));
typedef __bf16 bf16x4 __attribute__((ext_vector_type(4)));
typedef float floatx4 __attribute__((ext_vector_type(4)));
typedef _Float16 f16x8 __attribute__((ext_vector_type(8)));

#define MFMA16(a, b, c) __builtin_amdgcn_mfma_f32_16x16x32_bf16((a), (b), (c), 0, 0, 0)

// raw v_exp_f32 (2^x) when available
#if defined(__has_builtin)
#if __has_builtin(__builtin_amdgcn_exp2f)
#define EXP2F __builtin_amdgcn_exp2f
#endif
#endif
#ifndef EXP2F
#define EXP2F exp2f
#endif

// pack two fp32 -> two bf16 (round-to-nearest), single instruction
__device__ __forceinline__ unsigned pk_bf16(float a, float b) {
  unsigned r;
  asm("v_cvt_pk_bf16_f32 %0, %1, %2" : "=v"(r) : "v"(a), "v"(b));
  return r;
}

__device__ __forceinline__ void gl_lds16(const void* g, void* l) {
  __builtin_amdgcn_global_load_lds((__attribute__((address_space(1))) void*)(g),
                                   (__attribute__((address_space(3))) void*)(l),
                                   16, 0, 0);
}

// ---------------------------------------------------------------------------
// Fused prep: blocks [0,4096) cast x; [4096,4864) transpose w_qkv;
// [4864,5120) transpose w_out.
__global__ __launch_bounds__(256) void prep(const float* __restrict__ x,
                                            const float* __restrict__ w_qkv,
                                            const float* __restrict__ w_out,
                                            __bf16* __restrict__ xb,
                                            __bf16* __restrict__ wqkvt,
                                            __bf16* __restrict__ woutt) {
  __shared__ float tile[64][65];
  const int bid = blockIdx.x, t = threadIdx.x;
  if (bid < 4096) {
    int i = (bid * 256 + t) * 4;
    float4 v = *(const float4*)(x + i);
    bf16x4 o = { (__bf16)v.x, (__bf16)v.y, (__bf16)v.z, (__bf16)v.w };
    *(bf16x4*)(xb + i) = o;
    return;
  }
  const float* w;
  __bf16* wt;
  int K = 1024, N, k0, n0;
  if (bid < 4864) {
    int i = bid - 4096;  // 16 x 48
    w = w_qkv; wt = wqkvt; N = 3072; k0 = (i & 15) * 64; n0 = (i >> 4) * 64;
  } else {
    int i = bid - 4864;  // 16 x 16
    w = w_out; wt = woutt; N = 1024; k0 = (i & 15) * 64; n0 = (i >> 4) * 64;
  }
  for (int j = 0; j < 16; ++j) {
    int e = j * 256 + t, r = e >> 6, c = e & 63;
    tile[r][c] = w[(size_t)(k0 + r) * N + n0 + c];
  }
  __syncthreads();
  for (int j = 0; j < 16; ++j) {
    int e = j * 256 + t, r = e >> 6, c = e & 63;
    wt[(size_t)(n0 + r) * K + k0 + c] = (__bf16)tile[c][r];
  }
}

// ---------------------------------------------------------------------------
// QKV GEMM (m97 structure + XOR chunk swizzle). A[4096,1024] @ wqkvt[3072,1024]^T.
// cols <1024 (Q, pre-scaled by 0.125*log2e) and [1024,2048) (K) -> qkb;
// cols >=2048 (V) -> vtg d-major.
__global__ __launch_bounds__(256) void gemm_qkv(const __bf16* __restrict__ A,
                                                const __bf16* __restrict__ Bt,
                                                __bf16* __restrict__ qkb,
                                                __bf16* __restrict__ vt) {
  constexpr int K = 1024;
  constexpr float QSCALE = 0.18033688f;  // 0.125 * log2(e)
  __shared__ __align__(16) __bf16 aS[128 * 32];
  __shared__ __align__(16) __bf16 bS[128 * 32];
  const int t = threadIdx.x;
  const int lane = t & 63, wave = t >> 6;
  const int l15 = lane & 15, quad = lane >> 4;
  const int wm = wave >> 1, wn = wave & 1;
  const int m0 = blockIdx.y * 128, n0 = blockIdx.x * 128;

  const floatx4 fzero = {0.f, 0.f, 0.f, 0.f};
  floatx4 acc[4][4];
  for (int mt = 0; mt < 4; ++mt)
    for (int nt = 0; nt < 4; ++nt) acc[mt][nt] = fzero;

  const int arow = t >> 2;
  const int ach = ((t & 3) ^ (arow & 3)) * 8;  // source-chunk swizzle
  const __bf16* gA0 = A + (size_t)(m0 + arow) * K + ach;
  const __bf16* gA1 = gA0 + (size_t)64 * K;
  const __bf16* gB0 = Bt + (size_t)(n0 + arow) * K + ach;
  const __bf16* gB1 = gB0 + (size_t)64 * K;
  const int swz = (quad ^ (l15 & 3)) * 8;

  for (int k0 = 0; k0 < K; k0 += 32) {
    __syncthreads();
    gl_lds16(gA0 + k0, (char*)aS + t * 16);
    gl_lds16(gA1 + k0, (char*)aS + 4096 + t * 16);
    gl_lds16(gB0 + k0, (char*)bS + t * 16);
    gl_lds16(gB1 + k0, (char*)bS + 4096 + t * 16);
    __syncthreads();

    bf16x8 af[4], bfr[4];
    for (int mt = 0; mt < 4; ++mt)
      af[mt] = *(const bf16x8*)(aS + (wm * 64 + mt * 16 + l15) * 32 + swz);
    for (int nt = 0; nt < 4; ++nt)
      bfr[nt] = *(const bf16x8*)(bS + (wn * 64 + nt * 16 + l15) * 32 + swz);
    for (int mt = 0; mt < 4; ++mt)
      for (int nt = 0; nt < 4; ++nt)
        acc[mt][nt] = MFMA16(af[mt], bfr[nt], acc[mt][nt]);
  }

  // C/D layout: col = lane&15, row = quad*4 + reg
  for (int mt = 0; mt < 4; ++mt) {
    int row = m0 + wm * 64 + mt * 16 + quad * 4;
    for (int nt = 0; nt < 4; ++nt) {
      int col0 = n0 + wn * 64 + nt * 16;
      if (col0 >= 2048) {
        // V tile -> vt[bh][d][s]; lane holds 4 consecutive s at fixed d
        int dfull = col0 + l15 - 2048;
        int bh = ((row >> 11) << 4) + (dfull >> 6);
        int d = dfull & 63, s0 = row & 2047;
        bf16x4 pk = { (__bf16)acc[mt][nt][0], (__bf16)acc[mt][nt][1],
                      (__bf16)acc[mt][nt][2], (__bf16)acc[mt][nt][3] };
        *(bf16x4*)(vt + ((size_t)bh * 64 + d) * 2048 + s0) = pk;
      } else {
        float sc = (col0 < 1024) ? QSCALE : 1.0f;
        int col = col0 + l15;
        __bf16* cp = qkb + (size_t)row * 2048 + col;
        for (int r = 0; r < 4; ++r) cp[(size_t)r * 2048] = (__bf16)(acc[mt][nt][r] * sc);
      }
    }
  }
}

// ---------------------------------------------------------------------------
// GEMM2: C[4096,1024] fp32 = aout[4096,1024]bf16 @ woutt[1024,1024]^T.
// 128(M)x64(N) tiles -> grid 512 = 2 blocks/CU. Wave w owns rows w*32..+31.
__global__ __launch_bounds__(256) void gemm_n64(const __bf16* __restrict__ A,
                                                const __bf16* __restrict__ Bt,
                                                float* __restrict__ C) {
  constexpr int K = 1024, N = 1024;
  __shared__ __align__(16) __bf16 aS[128 * 32];
  __shared__ __align__(16) __bf16 bS[64 * 32];
  const int t = threadIdx.x;
  const int lane = t & 63, wave = t >> 6;
  const int l15 = lane & 15, quad = lane >> 4;
  const int m0 = blockIdx.y * 128, n0 = blockIdx.x * 64;

  const floatx4 fzero = {0.f, 0.f, 0.f, 0.f};
  floatx4 acc[2][4];
  for (int mt = 0; mt < 2; ++mt)
    for (int nt = 0; nt < 4; ++nt) acc[mt][nt] = fzero;

  const int arow = t >> 2;
  const int ach = ((t & 3) ^ (arow & 3)) * 8;
  const __bf16* gA0 = A + (size_t)(m0 + arow) * K + ach;
  const __bf16* gA1 = gA0 + (size_t)64 * K;
  const __bf16* gB0 = Bt + (size_t)(n0 + arow) * K + ach;
  const int swz = (quad ^ (l15 & 3)) * 8;

  for (int k0 = 0; k0 < K; k0 += 32) {
    __syncthreads();
    gl_lds16(gA0 + k0, (char*)aS + t * 16);
    gl_lds16(gA1 + k0, (char*)aS + 4096 + t * 16);
    gl_lds16(gB0 + k0, (char*)bS + t * 16);
    __syncthreads();

    bf16x8 af[2], bfr[4];
    for (int mt = 0; mt < 2; ++mt)
      af[mt] = *(const bf16x8*)(aS + (wave * 32 + mt * 16 + l15) * 32 + swz);
    for (int nt = 0; nt < 4; ++nt)
      bfr[nt] = *(const bf16x8*)(bS + (nt * 16 + l15) * 32 + swz);
    for (int mt = 0; mt < 2; ++mt)
      for (int nt = 0; nt < 4; ++nt)
        acc[mt][nt] = MFMA16(af[mt], bfr[nt], acc[mt][nt]);
  }

  for (int mt = 0; mt < 2; ++mt) {
    int row = m0 + wave * 32 + mt * 16 + quad * 4;
    for (int nt = 0; nt < 4; ++nt) {
      int col = n0 + nt * 16 + l15;
      float* cp = C + (size_t)row * N + col;
      for (int r = 0; r < 4; ++r) cp[(size_t)r * N] = acc[mt][nt][r];
    }
  }
}

// ---------------------------------------------------------------------------
// Flash attention partial, S^T form. Grid 1024, XCD-pinned:
// id -> xcd=id&7, r=id>>3 in [0,128): bh = xcd*4 + (r>>5), qb = (r>>1)&15,
// g = r&1 (key half). Both g-blocks of a (bh,qb) share the xcd -> each bh's
// 512KB K/V set stays in one XCD's L2 (4 bh x 512KB = 2MB < 4MB).
//
// Body = the proven R3 kernel verbatim (256 thr / 4 waves / 32 Q-rows per
// wave, K/V double-buffered via gl_lds16, one __syncthreads per key-iter,
// in-register P via cvt_pk + permlane32/16 swaps), restricted to keys
// [g*1024, g*1024+1024) -> 16 iters. 4 blocks/CU = 4 independent barrier
// streams per SIMD (vs 2 in R2/R3 -- the MFMA/VALU overlap lever).
//
// Epilogue stores RAW partials (no normalize): O_g fp16 [4096][1024],
// l_g fp32 [4096*16] (one value per (token-row, head)). Exact split-K:
// out = (O0+O1)/(l0+l1) done by the combine kernel.
__global__ __launch_bounds__(256, 4) void flash_attn(const __bf16* __restrict__ qkb,
                                                     const __bf16* __restrict__ vt,
                                                     _Float16* __restrict__ o0,
                                                     _Float16* __restrict__ o1,
                                                     float* __restrict__ l0,
                                                     float* __restrict__ l1) {
  __shared__ __align__(16) __bf16 kS[2 * 64 * 64];  // [buf][key][d] swizzled, 16 KB
  __shared__ __align__(16) __bf16 vS[2 * 64 * 64];  // [buf][d][key] swizzled, 16 KB

  const int t = threadIdx.x;
  const int lane = t & 63, wave = t >> 6;
  const int l15 = lane & 15, quad = lane >> 4;
  const int id = blockIdx.x;
  const int xcd = id & 7, r = id >> 3;
  const int bh = xcd * 4 + (r >> 5), qb = (r >> 1) & 15, g = r & 1;
  const int b = bh >> 4, h = bh & 15;
  const int kofs = g << 10;  // key-range offset: [kofs, kofs+1024)

  // Q B-fragments (lane: n=qrow=l15, k=d=quad*8+j), 2 q-tiles x 2 d-halves
  bf16x8 qf[2][2];
  for (int qt = 0; qt < 2; ++qt) {
    const __bf16* qp = qkb +
        (size_t)(b * 2048 + qb * 128 + wave * 32 + qt * 16 + l15) * 2048 + h * 64 + quad * 8;
    qf[qt][0] = *(const bf16x8*)qp;
    qf[qt][1] = *(const bf16x8*)(qp + 32);
  }

  // ones B-fragment for the denominator MFMA
  bf16x8 onef;
  for (int j = 0; j < 8; ++j) onef[j] = (__bf16)1.0f;

  const floatx4 fzero = {0.f, 0.f, 0.f, 0.f};
  floatx4 oacc[2][4], lacc[2];
  for (int qt = 0; qt < 2; ++qt) {
    lacc[qt] = fzero;
    for (int dt = 0; dt < 4; ++dt) oacc[qt][dt] = fzero;
  }

  // Staging pointers (source-chunk swizzle: slot s -> row s>>3, chunk (s&7)^(row&7))
  // 256 threads cover half a 64x64 tile per gl_lds16; two calls per tile.
  const int srow = t >> 3, schk = (t & 7) ^ (srow & 7);
  const __bf16* kg0 =
      qkb + (size_t)(b * 2048 + kofs + srow) * 2048 + 1024 + h * 64 + schk * 8;
  const __bf16* kg1 = kg0 + (size_t)32 * 2048;
  const __bf16* vg0 =
      vt + (size_t)bh * 64 * 2048 + (size_t)srow * 2048 + kofs + schk * 8;
  const __bf16* vg1 = vg0 + (size_t)32 * 2048;

  const int l7 = l15 & 7;

  // prologue: stage tile 0 into buffer 0
  gl_lds16(kg0, (char*)kS + t * 16);
  gl_lds16(kg1, (char*)kS + 4096 + t * 16);
  gl_lds16(vg0, (char*)vS + t * 16);
  gl_lds16(vg1, (char*)vS + 4096 + t * 16);

  for (int nb = 0; nb < 16; ++nb) {
    __syncthreads();  // staging for nb landed; prev iter's reads of other buf done

    if (nb < 15) {  // stage nb+1 into the other buffer; flies during compute
      const size_t n1 = (size_t)(nb + 1) * 64;
      const int oB = ((nb + 1) & 1) * 8192;
      gl_lds16(kg0 + n1 * 2048, (char*)kS + oB + t * 16);
      gl_lds16(kg1 + n1 * 2048, (char*)kS + oB + 4096 + t * 16);
      gl_lds16(vg0 + n1, (char*)vS + oB + t * 16);
      gl_lds16(vg1 + n1, (char*)vS + oB + 4096 + t * 16);
    }

    const __bf16* kC = kS + (nb & 1) * 4096;
    const __bf16* vC = vS + (nb & 1) * 4096;

    // K A-fragments (lane: m=key=nt*16+l15, k=d=ks*32+quad*8+j)
    bf16x8 kf[4][2];
    for (int nt = 0; nt < 4; ++nt)
      for (int ks = 0; ks < 2; ++ks)
        kf[nt][ks] = *(const bf16x8*)(kC + (nt * 16 + l15) * 64 +
                                      ((ks * 4 + quad) ^ l7) * 8);
    // V B-fragments (lane: n=d=dt*16+l15, k=key=ks*32+quad*8+j)
    bf16x8 vf[2][4];
    for (int ks = 0; ks < 2; ++ks)
      for (int dt = 0; dt < 4; ++dt)
        vf[ks][dt] = *(const bf16x8*)(vC + (dt * 16 + l15) * 64 +
                                      ((ks * 4 + quad) ^ l7) * 8);

    // S^T = K Q^T for both q-tiles (C layout: col=qrow=l15, row=key=quad*4+r)
    floatx4 sa[2][4];
    __builtin_amdgcn_s_setprio(1);
    for (int qt = 0; qt < 2; ++qt)
      for (int nt = 0; nt < 4; ++nt) {
        floatx4 a = fzero;
        a = MFMA16(kf[nt][0], qf[qt][0], a);
        a = MFMA16(kf[nt][1], qf[qt][1], a);
        sa[qt][nt] = a;
      }
    __builtin_amdgcn_s_setprio(0);

    // Per q-tile: exp, pack, permlane-redistribute, PV MFMA.  sm(qt1)'s VALU
    // issues while PV(qt0)'s MFMAs are still executing.
    for (int qt = 0; qt < 2; ++qt) {
      bf16x8 pa[2];
      for (int ks = 0; ks < 2; ++ks) {
        const int n0 = 2 * ks, n1 = 2 * ks + 1;
        float e00 = EXP2F(sa[qt][n0][0]), e01 = EXP2F(sa[qt][n0][1]);
        float e02 = EXP2F(sa[qt][n0][2]), e03 = EXP2F(sa[qt][n0][3]);
        float e10 = EXP2F(sa[qt][n1][0]), e11 = EXP2F(sa[qt][n1][1]);
        float e12 = EXP2F(sa[qt][n1][2]), e13 = EXP2F(sa[qt][n1][3]);
        unsigned x0 = pk_bf16(e00, e01), x1 = pk_bf16(e02, e03);
        unsigned y0 = pk_bf16(e10, e11), y1 = pk_bf16(e12, e13);
        // (D0,D2) from (x0,y0); (D1,D3) from (x1,y1)
        unsigned d0 = x0, d2 = y0;
        asm("v_permlane32_swap_b32 %0, %1" : "+v"(d0), "+v"(d2));
        asm("v_permlane16_swap_b32 %0, %1" : "+v"(d0), "+v"(d2));
        unsigned d1 = x1, d3 = y1;
        asm("v_permlane32_swap_b32 %0, %1" : "+v"(d1), "+v"(d3));
        asm("v_permlane16_swap_b32 %0, %1" : "+v"(d1), "+v"(d3));
        union { unsigned u[4]; bf16x8 v8; } pu;
        pu.u[0] = d0; pu.u[1] = d1; pu.u[2] = d2; pu.u[3] = d3;
        pa[ks] = pu.v8;
      }
      // O += P V ; l += P @ ones  (A-frag: m=qrow=l15, k=key)
      __builtin_amdgcn_s_setprio(1);
      for (int ks = 0; ks < 2; ++ks) {
        for (int dt = 0; dt < 4; ++dt)
          oacc[qt][dt] = MFMA16(pa[ks], vf[ks][dt], oacc[qt][dt]);
        lacc[qt] = MFMA16(pa[ks], onef, lacc[qt]);
      }
      __builtin_amdgcn_s_setprio(0);
    }
  }

  // Epilogue: store RAW fp16 O partial + fp32 l partial (no normalize).
  _Float16* og = g ? o1 : o0;
  float* lg = g ? l1 : l0;
  for (int qt = 0; qt < 2; ++qt) {
    const int row0 = b * 2048 + qb * 128 + wave * 32 + qt * 16 + quad * 4;
    _Float16* op = og + (size_t)row0 * 1024 + h * 64;
    for (int dt = 0; dt < 4; ++dt)
      for (int r2 = 0; r2 < 4; ++r2)
        op[(size_t)r2 * 1024 + dt * 16 + l15] = (_Float16)oacc[qt][dt][r2];
    if (l15 == 0) {  // all 16 cols of lacc hold the same row-sum
      float* lp = lg + (size_t)row0 * 16 + h;
      for (int r2 = 0; r2 < 4; ++r2) lp[(size_t)r2 * 16] = lacc[qt][r2];
    }
  }
}

// ---------------------------------------------------------------------------
// Split-K combine: aout[i] = (O0[i]+O1[i]) / (l0[i>>6]+l1[i>>6]), bf16,
// written IN-PLACE over O1's buffer (each thread reads then writes the same
// 16 bytes; data dependence orders it; disjoint across threads).
// i>>6 = token_row*16 + h since cols are h*64+d with d in [0,64).
__global__ __launch_bounds__(256) void combine(const _Float16* __restrict__ o0,
                                               _Float16* __restrict__ o1,
                                               const float* __restrict__ l0,
                                               const float* __restrict__ l1) {
  const size_t i = ((size_t)blockIdx.x * 256 + threadIdx.x) * 8;
  f16x8 a = *(const f16x8*)(o0 + i);
  f16x8 c = *(const f16x8*)(o1 + i);
  const int li = (int)(i >> 6);
  const float inv = 1.0f / (l0[li] + l1[li]);
  bf16x8 res;
  for (int j = 0; j < 8; ++j)
    res[j] = (__bf16)(((float)a[j] + (float)c[j]) * inv);
  *(bf16x8*)((__bf16*)o1 + i) = res;
}

// ---------------------------------------------------------------------------
extern "C" void kernel_launch(void* const* d_in, const int* in_sizes, int n_in,
                              void* d_out, int out_size, void* d_ws, size_t ws_size,
                              hipStream_t stream) {
  const float* x = (const float*)d_in[0];      // [4096, 1024]
  const float* w_qkv = (const float*)d_in[1];  // [1024, 3072]
  const float* w_out = (const float*)d_in[2];  // [1024, 1024]
  float* out = (float*)d_out;                  // [4096, 1024]

  char* ws = (char*)d_ws;
  __bf16* xb = (__bf16*)(ws);                             // [0,8) MB (prep->gemm_qkv)
  _Float16* o0 = (_Float16*)(ws);                         // [0,8) MB (flash->combine)
  __bf16* wqkvt = (__bf16*)(ws + ((size_t)8 << 20));      // [8,14) MB
  float* l0 = (float*)(ws + ((size_t)14 << 20));          // [14,14.25) MB
  float* l1 = (float*)(ws + ((size_t)14 << 20) + 262144); // [14.25,14.5) MB
  __bf16* qkb = (__bf16*)(ws + ((size_t)16 << 20));       // [16,32) MB
  __bf16* vtg = (__bf16*)(ws + ((size_t)32 << 20));       // [32,40) MB
  _Float16* o1 = (_Float16*)(ws + ((size_t)40 << 20));    // [40,48) MB (flash->combine)
  __bf16* aout = (__bf16*)(ws + ((size_t)40 << 20));      // [40,48) MB (combine->gemm_n64)
  __bf16* woutt = (__bf16*)(ws + ((size_t)48 << 20));     // [48,50) MB

  prep<<<5120, 256, 0, stream>>>(x, w_qkv, w_out, xb, wqkvt, woutt);
  gemm_qkv<<<dim3(24, 32), 256, 0, stream>>>(xb, wqkvt, qkb, vtg);
  flash_attn<<<1024, 256, 0, stream>>>(qkb, vtg, o0, o1, l0, l1);
  combine<<<2048, 256, 0, stream>>>(o0, o1, l0, l1);
  gemm_n64<<<dim3(16, 32), 256, 0, stream>>>(aout, woutt, out);
}

// Round 6
// 172.857 us; speedup vs baseline: 1.4371x; 1.4371x over previous
//
#include <hip/hip_runtime.h>

// ---------------------------------------------------------------------------
// MultiHeadAttention forward, MI355X/gfx950.
// B=2, S=2048, DIM=1024, H=16, d=64.  All GEMM-shaped compute on
// mfma_f32_16x16x32_bf16; softmax in fp32 (fixed-max, denominator via
// ones-MFMA over the rounded P -> self-normalizing).
//
// Pipeline (4 launches):
//   prep:       cast x->bf16; transpose+cast w_qkv, w_out  (fused)
//   gemm_qkv:   qkb[4096,2048] = {Q,K} thirds of xb @ wqkvt^T (Q pre-scaled
//               by 0.125*log2e so flash softmax is a bare v_exp_f32); V tiles
//               written transposed straight to vtg [B*H, 64, 2048] (d-major)
//   flash_attn: R3 shape (grid 512 XCD-pinned, 256 thr / 4 waves / 32 Q-rows
//               per wave, 32 KB LDS, in-register P via permlane32/16 swaps).
//               R6: software-pipelined key loop -- per iter: issue ds_reads
//               for tile n, then softmax+PV of tile n-1 (registers only,
//               no waits), then QK of tile n. The LDS->MFMA and MFMA->exp
//               latencies cross the iteration boundary and hide under ~600cy
//               of independent work (R5 analysis: R3 was dependency-stall
//               bound at ~36% issue occupancy per SIMD, not pipe-bound).
//   gemm_n64:   d_out = aout @ woutt^T  (128x64 tiles, 2 blocks/CU)
//
// Workspace layout:
//   [ 0, 8) MB  xb     (prep->gemm_qkv)
//   [ 8,14) MB  wqkvt  (prep->gemm_qkv)
//   [16,32) MB  qkb  [4096][2048] bf16  (gemm_qkv->flash)
//   [32,40) MB  vtg  [B*H][64][2048]    (gemm_qkv->flash)
//   [40,48) MB  aout [4096][1024] bf16  (flash->gemm_n64)
//   [48,50) MB  woutt                   (prep->gemm_n64)
// ---------------------------------------------------------------------------

typedef __bf16 bf16x8 __attribute__((ext_vector_type(8)));
typedef __bf16 bf16x4 __attribute__((ext_vector_type(4)));
typedef float floatx4 __attribute__((ext_vector_type(4)));

#define MFMA16(a, b, c) __builtin_amdgcn_mfma_f32_16x16x32_bf16((a), (b), (c), 0, 0, 0)

// raw v_exp_f32 (2^x) when available
#if defined(__has_builtin)
#if __has_builtin(__builtin_amdgcn_exp2f)
#define EXP2F __builtin_amdgcn_exp2f
#endif
#endif
#ifndef EXP2F
#define EXP2F exp2f
#endif

// pack two fp32 -> two bf16 (round-to-nearest), single instruction
__device__ __forceinline__ unsigned pk_bf16(float a, float b) {
  unsigned r;
  asm("v_cvt_pk_bf16_f32 %0, %1, %2" : "=v"(r) : "v"(a), "v"(b));
  return r;
}

__device__ __forceinline__ void gl_lds16(const void* g, void* l) {
  __builtin_amdgcn_global_load_lds((__attribute__((address_space(1))) void*)(g),
                                   (__attribute__((address_space(3))) void*)(l),
                                   16, 0, 0);
}

// ---------------------------------------------------------------------------
// Fused prep: blocks [0,4096) cast x; [4096,4864) transpose w_qkv;
// [4864,5120) transpose w_out.
__global__ __launch_bounds__(256) void prep(const float* __restrict__ x,
                                            const float* __restrict__ w_qkv,
                                            const float* __restrict__ w_out,
                                            __bf16* __restrict__ xb,
                                            __bf16* __restrict__ wqkvt,
                                            __bf16* __restrict__ woutt) {
  __shared__ float tile[64][65];
  const int bid = blockIdx.x, t = threadIdx.x;
  if (bid < 4096) {
    int i = (bid * 256 + t) * 4;
    float4 v = *(const float4*)(x + i);
    bf16x4 o = { (__bf16)v.x, (__bf16)v.y, (__bf16)v.z, (__bf16)v.w };
    *(bf16x4*)(xb + i) = o;
    return;
  }
  const float* w;
  __bf16* wt;
  int K = 1024, N, k0, n0;
  if (bid < 4864) {
    int i = bid - 4096;  // 16 x 48
    w = w_qkv; wt = wqkvt; N = 3072; k0 = (i & 15) * 64; n0 = (i >> 4) * 64;
  } else {
    int i = bid - 4864;  // 16 x 16
    w = w_out; wt = woutt; N = 1024; k0 = (i & 15) * 64; n0 = (i >> 4) * 64;
  }
  for (int j = 0; j < 16; ++j) {
    int e = j * 256 + t, r = e >> 6, c = e & 63;
    tile[r][c] = w[(size_t)(k0 + r) * N + n0 + c];
  }
  __syncthreads();
  for (int j = 0; j < 16; ++j) {
    int e = j * 256 + t, r = e >> 6, c = e & 63;
    wt[(size_t)(n0 + r) * K + k0 + c] = (__bf16)tile[c][r];
  }
}

// ---------------------------------------------------------------------------
// QKV GEMM (m97 structure + XOR chunk swizzle). A[4096,1024] @ wqkvt[3072,1024]^T.
// cols <1024 (Q, pre-scaled by 0.125*log2e) and [1024,2048) (K) -> qkb;
// cols >=2048 (V) -> vtg d-major.
__global__ __launch_bounds__(256) void gemm_qkv(const __bf16* __restrict__ A,
                                                const __bf16* __restrict__ Bt,
                                                __bf16* __restrict__ qkb,
                                                __bf16* __restrict__ vt) {
  constexpr int K = 1024;
  constexpr float QSCALE = 0.18033688f;  // 0.125 * log2(e)
  __shared__ __align__(16) __bf16 aS[128 * 32];
  __shared__ __align__(16) __bf16 bS[128 * 32];
  const int t = threadIdx.x;
  const int lane = t & 63, wave = t >> 6;
  const int l15 = lane & 15, quad = lane >> 4;
  const int wm = wave >> 1, wn = wave & 1;
  const int m0 = blockIdx.y * 128, n0 = blockIdx.x * 128;

  const floatx4 fzero = {0.f, 0.f, 0.f, 0.f};
  floatx4 acc[4][4];
  for (int mt = 0; mt < 4; ++mt)
    for (int nt = 0; nt < 4; ++nt) acc[mt][nt] = fzero;

  const int arow = t >> 2;
  const int ach = ((t & 3) ^ (arow & 3)) * 8;  // source-chunk swizzle
  const __bf16* gA0 = A + (size_t)(m0 + arow) * K + ach;
  const __bf16* gA1 = gA0 + (size_t)64 * K;
  const __bf16* gB0 = Bt + (size_t)(n0 + arow) * K + ach;
  const __bf16* gB1 = gB0 + (size_t)64 * K;
  const int swz = (quad ^ (l15 & 3)) * 8;

  for (int k0 = 0; k0 < K; k0 += 32) {
    __syncthreads();
    gl_lds16(gA0 + k0, (char*)aS + t * 16);
    gl_lds16(gA1 + k0, (char*)aS + 4096 + t * 16);
    gl_lds16(gB0 + k0, (char*)bS + t * 16);
    gl_lds16(gB1 + k0, (char*)bS + 4096 + t * 16);
    __syncthreads();

    bf16x8 af[4], bfr[4];
    for (int mt = 0; mt < 4; ++mt)
      af[mt] = *(const bf16x8*)(aS + (wm * 64 + mt * 16 + l15) * 32 + swz);
    for (int nt = 0; nt < 4; ++nt)
      bfr[nt] = *(const bf16x8*)(bS + (wn * 64 + nt * 16 + l15) * 32 + swz);
    for (int mt = 0; mt < 4; ++mt)
      for (int nt = 0; nt < 4; ++nt)
        acc[mt][nt] = MFMA16(af[mt], bfr[nt], acc[mt][nt]);
  }

  // C/D layout: col = lane&15, row = quad*4 + reg
  for (int mt = 0; mt < 4; ++mt) {
    int row = m0 + wm * 64 + mt * 16 + quad * 4;
    for (int nt = 0; nt < 4; ++nt) {
      int col0 = n0 + wn * 64 + nt * 16;
      if (col0 >= 2048) {
        // V tile -> vt[bh][d][s]; lane holds 4 consecutive s at fixed d
        int dfull = col0 + l15 - 2048;
        int bh = ((row >> 11) << 4) + (dfull >> 6);
        int d = dfull & 63, s0 = row & 2047;
        bf16x4 pk = { (__bf16)acc[mt][nt][0], (__bf16)acc[mt][nt][1],
                      (__bf16)acc[mt][nt][2], (__bf16)acc[mt][nt][3] };
        *(bf16x4*)(vt + ((size_t)bh * 64 + d) * 2048 + s0) = pk;
      } else {
        float sc = (col0 < 1024) ? QSCALE : 1.0f;
        int col = col0 + l15;
        __bf16* cp = qkb + (size_t)row * 2048 + col;
        for (int r = 0; r < 4; ++r) cp[(size_t)r * 2048] = (__bf16)(acc[mt][nt][r] * sc);
      }
    }
  }
}

// ---------------------------------------------------------------------------
// GEMM2: C[4096,1024] fp32 = aout[4096,1024]bf16 @ woutt[1024,1024]^T.
// 128(M)x64(N) tiles -> grid 512 = 2 blocks/CU. Wave w owns rows w*32..+31.
__global__ __launch_bounds__(256) void gemm_n64(const __bf16* __restrict__ A,
                                                const __bf16* __restrict__ Bt,
                                                float* __restrict__ C) {
  constexpr int K = 1024, N = 1024;
  __shared__ __align__(16) __bf16 aS[128 * 32];
  __shared__ __align__(16) __bf16 bS[64 * 32];
  const int t = threadIdx.x;
  const int lane = t & 63, wave = t >> 6;
  const int l15 = lane & 15, quad = lane >> 4;
  const int m0 = blockIdx.y * 128, n0 = blockIdx.x * 64;

  const floatx4 fzero = {0.f, 0.f, 0.f, 0.f};
  floatx4 acc[2][4];
  for (int mt = 0; mt < 2; ++mt)
    for (int nt = 0; nt < 4; ++nt) acc[mt][nt] = fzero;

  const int arow = t >> 2;
  const int ach = ((t & 3) ^ (arow & 3)) * 8;
  const __bf16* gA0 = A + (size_t)(m0 + arow) * K + ach;
  const __bf16* gA1 = gA0 + (size_t)64 * K;
  const __bf16* gB0 = Bt + (size_t)(n0 + arow) * K + ach;
  const int swz = (quad ^ (l15 & 3)) * 8;

  for (int k0 = 0; k0 < K; k0 += 32) {
    __syncthreads();
    gl_lds16(gA0 + k0, (char*)aS + t * 16);
    gl_lds16(gA1 + k0, (char*)aS + 4096 + t * 16);
    gl_lds16(gB0 + k0, (char*)bS + t * 16);
    __syncthreads();

    bf16x8 af[2], bfr[4];
    for (int mt = 0; mt < 2; ++mt)
      af[mt] = *(const bf16x8*)(aS + (wave * 32 + mt * 16 + l15) * 32 + swz);
    for (int nt = 0; nt < 4; ++nt)
      bfr[nt] = *(const bf16x8*)(bS + (nt * 16 + l15) * 32 + swz);
    for (int mt = 0; mt < 2; ++mt)
      for (int nt = 0; nt < 4; ++nt)
        acc[mt][nt] = MFMA16(af[mt], bfr[nt], acc[mt][nt]);
  }

  for (int mt = 0; mt < 2; ++mt) {
    int row = m0 + wave * 32 + mt * 16 + quad * 4;
    for (int nt = 0; nt < 4; ++nt) {
      int col = n0 + nt * 16 + l15;
      float* cp = C + (size_t)row * N + col;
      for (int r = 0; r < 4; ++r) cp[(size_t)r * N] = acc[mt][nt][r];
    }
  }
}

// ---------------------------------------------------------------------------
// Flash attention, S^T form, full S per block. Grid 512, XCD-pinned:
// id -> xcd=id&7, slot=id>>3; bh = xcd*4 + slot/16, qb = slot%16 -> each bh's
// 512KB K/V working set pinned to one XCD's L2 (4 bh x 512KB = 2MB < 4MB).
// 256 threads / 4 waves, each wave owns 32 Q-rows (qt=2); 2 blocks/CU.
//
// R6 software pipeline (1-tile lookahead): per iter, program order is
//   barrier -> stage(n+1) -> ds_read kf/vf(n) -> sm+PV(n-1) -> QK(n)
// sm+PV(n-1) runs on registers (sa_prev, vf_prev) with ZERO outstanding
// waits; the ds_read->QK lgkmcnt and the QK->exp MFMA-result latency both
// cross the iteration boundary and hide under ~600cy of independent issue.
// Buffer invariants identical to R3: tile n lives in buf n&1; the barrier
// at iter n's top drains stage(n) and all reads of buf (n+1)&1.
//
// In-register P (R2): after S^T = K Q^T, lane 16q+c holds
// P[key=16nt+4q+r][qrow=c]; PV A-fragment built with cvt_pk_bf16 +
// permlane32/16 swaps, register-only. Denominator l via ones-MFMA over the
// rounded P (self-normalizing; lane-aligned with O rows -> no shuffles).
__global__ __launch_bounds__(256, 2) void flash_attn(const __bf16* __restrict__ qkb,
                                                     const __bf16* __restrict__ vt,
                                                     __bf16* __restrict__ out) {
  __shared__ __align__(16) __bf16 kS[2 * 64 * 64];  // [buf][key][d] swizzled, 16 KB
  __shared__ __align__(16) __bf16 vS[2 * 64 * 64];  // [buf][d][key] swizzled, 16 KB

  const int t = threadIdx.x;
  const int lane = t & 63, wave = t >> 6;
  const int l15 = lane & 15, quad = lane >> 4;
  const int id = blockIdx.x;
  const int xcd = id & 7, slot = id >> 3;
  const int bh = xcd * 4 + (slot >> 4), qb = slot & 15;
  const int b = bh >> 4, h = bh & 15;

  // Q B-fragments (lane: n=qrow=l15, k=d=quad*8+j), 2 q-tiles x 2 d-halves
  bf16x8 qf[2][2];
  for (int qt = 0; qt < 2; ++qt) {
    const __bf16* qp = qkb +
        (size_t)(b * 2048 + qb * 128 + wave * 32 + qt * 16 + l15) * 2048 + h * 64 + quad * 8;
    qf[qt][0] = *(const bf16x8*)qp;
    qf[qt][1] = *(const bf16x8*)(qp + 32);
  }

  // ones B-fragment for the denominator MFMA
  bf16x8 onef;
  for (int j = 0; j < 8; ++j) onef[j] = (__bf16)1.0f;

  const floatx4 fzero = {0.f, 0.f, 0.f, 0.f};
  floatx4 oacc[2][4], lacc[2];
  for (int qt = 0; qt < 2; ++qt) {
    lacc[qt] = fzero;
    for (int dt = 0; dt < 4; ++dt) oacc[qt][dt] = fzero;
  }

  // Staging pointers (source-chunk swizzle: slot s -> row s>>3, chunk (s&7)^(row&7))
  const int srow = t >> 3, schk = (t & 7) ^ (srow & 7);
  const __bf16* kg0 =
      qkb + (size_t)(b * 2048 + srow) * 2048 + 1024 + h * 64 + schk * 8;
  const __bf16* kg1 = kg0 + (size_t)32 * 2048;
  const __bf16* vg0 =
      vt + (size_t)bh * 64 * 2048 + (size_t)srow * 2048 + schk * 8;
  const __bf16* vg1 = vg0 + (size_t)32 * 2048;

  const int l7 = l15 & 7;

  // --- pipeline register state ---
  bf16x8 kf[4][2];
  bf16x8 vfA[2][4], vfB[2][4];
  floatx4 saA[2][4], saB[2][4];

  // stage tile n into buf n&1 (4 x gl_lds16, whole block covers 2 tiles)
  auto stage = [&](int tile) {
    const size_t n1 = (size_t)tile * 64;
    const int oB = (tile & 1) * 8192;
    gl_lds16(kg0 + n1 * 2048, (char*)kS + oB + t * 16);
    gl_lds16(kg1 + n1 * 2048, (char*)kS + oB + 4096 + t * 16);
    gl_lds16(vg0 + n1, (char*)vS + oB + t * 16);
    gl_lds16(vg1 + n1, (char*)vS + oB + 4096 + t * 16);
  };

  // ds_read K/V fragments of buf into kf / vf
  auto loadKV = [&](int buf, bf16x8 (&vf)[2][4]) {
    const __bf16* kC = kS + buf * 4096;
    const __bf16* vC = vS + buf * 4096;
    for (int nt = 0; nt < 4; ++nt)
      for (int ks = 0; ks < 2; ++ks)
        kf[nt][ks] = *(const bf16x8*)(kC + (nt * 16 + l15) * 64 +
                                      ((ks * 4 + quad) ^ l7) * 8);
    for (int ks = 0; ks < 2; ++ks)
      for (int dt = 0; dt < 4; ++dt)
        vf[ks][dt] = *(const bf16x8*)(vC + (dt * 16 + l15) * 64 +
                                      ((ks * 4 + quad) ^ l7) * 8);
  };

  // S^T = K Q^T for both q-tiles (C layout: col=qrow=l15, row=key=quad*4+r)
  auto qk = [&](floatx4 (&sa)[2][4]) {
    __builtin_amdgcn_s_setprio(1);
    for (int qt = 0; qt < 2; ++qt)
      for (int nt = 0; nt < 4; ++nt) {
        floatx4 a = fzero;
        a = MFMA16(kf[nt][0], qf[qt][0], a);
        a = MFMA16(kf[nt][1], qf[qt][1], a);
        sa[qt][nt] = a;
      }
    __builtin_amdgcn_s_setprio(0);
  };

  // softmax + PV for one tile (registers only -- no LDS, no waits)
  auto smpv = [&](floatx4 (&sa)[2][4], bf16x8 (&vf)[2][4]) {
    for (int qt = 0; qt < 2; ++qt) {
      bf16x8 pa[2];
      for (int ks = 0; ks < 2; ++ks) {
        const int n0 = 2 * ks, n1 = 2 * ks + 1;
        float e00 = EXP2F(sa[qt][n0][0]), e01 = EXP2F(sa[qt][n0][1]);
        float e02 = EXP2F(sa[qt][n0][2]), e03 = EXP2F(sa[qt][n0][3]);
        float e10 = EXP2F(sa[qt][n1][0]), e11 = EXP2F(sa[qt][n1][1]);
        float e12 = EXP2F(sa[qt][n1][2]), e13 = EXP2F(sa[qt][n1][3]);
        unsigned x0 = pk_bf16(e00, e01), x1 = pk_bf16(e02, e03);
        unsigned y0 = pk_bf16(e10, e11), y1 = pk_bf16(e12, e13);
        // (D0,D2) from (x0,y0); (D1,D3) from (x1,y1)
        unsigned d0 = x0, d2 = y0;
        asm("v_permlane32_swap_b32 %0, %1" : "+v"(d0), "+v"(d2));
        asm("v_permlane16_swap_b32 %0, %1" : "+v"(d0), "+v"(d2));
        unsigned d1 = x1, d3 = y1;
        asm("v_permlane32_swap_b32 %0, %1" : "+v"(d1), "+v"(d3));
        asm("v_permlane16_swap_b32 %0, %1" : "+v"(d1), "+v"(d3));
        union { unsigned u[4]; bf16x8 v8; } pu;
        pu.u[0] = d0; pu.u[1] = d1; pu.u[2] = d2; pu.u[3] = d3;
        pa[ks] = pu.v8;
      }
      __builtin_amdgcn_s_setprio(1);
      for (int ks = 0; ks < 2; ++ks) {
        for (int dt = 0; dt < 4; ++dt)
          oacc[qt][dt] = MFMA16(pa[ks], vf[ks][dt], oacc[qt][dt]);
        lacc[qt] = MFMA16(pa[ks], onef, lacc[qt]);
      }
      __builtin_amdgcn_s_setprio(0);
    }
  };

  // --- prologue: tile 0 ---
  stage(0);
  __syncthreads();   // stage(0) landed
  stage(1);          // flies during tile-0 QK
  loadKV(0, vfA);
  qk(saA);           // saA/vfA = tile 0

  // --- main pipeline: pairs (1,2),(3,4),...,(29,30) ---
  for (int nb = 1; nb < 31; nb += 2) {
    // iter nb (odd -> buf1): prev = A (tile nb-1), cur = B (tile nb)
    __syncthreads();           // stage(nb) landed; reads of buf0 drained
    stage(nb + 1);             // -> buf0 (<=30, always valid)
    loadKV(1, vfB);            // ds_reads issue; consumed only in qk(saB)
    smpv(saA, vfA);            // tile nb-1: registers only, zero waits
    qk(saB);                   // tile nb: lgkm wait hidden under smpv
    // iter nb+1 (even -> buf0): prev = B (tile nb), cur = A (tile nb+1)
    __syncthreads();           // stage(nb+1) landed; reads of buf1 drained
    stage(nb + 2);             // -> buf1 (<=31, always valid)
    loadKV(0, vfA);
    smpv(saB, vfB);            // tile nb
    qk(saA);                   // tile nb+1
  }

  // --- iter 31 (odd -> buf1) ---
  __syncthreads();             // stage(31) landed; reads of buf0 drained
  loadKV(1, vfB);
  smpv(saA, vfA);              // tile 30
  qk(saB);                     // tile 31
  smpv(saB, vfB);              // tile 31 (drain)

  // Epilogue: normalize (lacc rows == oacc rows lane-for-lane) and store.
  for (int qt = 0; qt < 2; ++qt) {
    float inv[4];
    for (int r = 0; r < 4; ++r) inv[r] = 1.f / lacc[qt][r];
    __bf16* ob = out +
        (size_t)(b * 2048 + qb * 128 + wave * 32 + qt * 16 + quad * 4) * 1024 + h * 64;
    for (int dt = 0; dt < 4; ++dt)
      for (int r = 0; r < 4; ++r)
        ob[(size_t)r * 1024 + dt * 16 + l15] = (__bf16)(oacc[qt][dt][r] * inv[r]);
  }
}

// ---------------------------------------------------------------------------
extern "C" void kernel_launch(void* const* d_in, const int* in_sizes, int n_in,
                              void* d_out, int out_size, void* d_ws, size_t ws_size,
                              hipStream_t stream) {
  const float* x = (const float*)d_in[0];      // [4096, 1024]
  const float* w_qkv = (const float*)d_in[1];  // [1024, 3072]
  const float* w_out = (const float*)d_in[2];  // [1024, 1024]
  float* out = (float*)d_out;                  // [4096, 1024]

  char* ws = (char*)d_ws;
  __bf16* xb = (__bf16*)(ws);                             // [0,8) MB
  __bf16* wqkvt = (__bf16*)(ws + ((size_t)8 << 20));      // [8,14) MB
  __bf16* qkb = (__bf16*)(ws + ((size_t)16 << 20));       // [16,32) MB
  __bf16* vtg = (__bf16*)(ws + ((size_t)32 << 20));       // [32,40) MB
  __bf16* aout = (__bf16*)(ws + ((size_t)40 << 20));      // [40,48) MB
  __bf16* woutt = (__bf16*)(ws + ((size_t)48 << 20));     // [48,50) MB

  prep<<<5120, 256, 0, stream>>>(x, w_qkv, w_out, xb, wqkvt, woutt);
  gemm_qkv<<<dim3(24, 32), 256, 0, stream>>>(xb, wqkvt, qkb, vtg);
  flash_attn<<<512, 256, 0, stream>>>(qkb, vtg, aout);
  gemm_n64<<<dim3(16, 32), 256, 0, stream>>>(aout, woutt, out);
}

// Round 7
// 172.092 us; speedup vs baseline: 1.4435x; 1.0044x over previous
//
#include <hip/hip_runtime.h>

// ---------------------------------------------------------------------------
// MultiHeadAttention forward, MI355X/gfx950.
// B=2, S=2048, DIM=1024, H=16, d=64.  All GEMM-shaped compute on
// mfma_f32_16x16x32_bf16; softmax in fp32 (fixed-max, denominator via
// ones-MFMA over the rounded P -> self-normalizing).
//
// Pipeline (4 launches):
//   prep:       cast x->bf16; transpose+cast w_qkv, w_out  (fused)
//   gemm_qkv:   qkb[4096,2048] = {Q,K} thirds of xb @ wqkvt^T (Q pre-scaled
//               by 0.125*log2e so flash softmax is a bare v_exp_f32); V tiles
//               written transposed straight to vtg [B*H, 64, 2048] (d-major)
//   flash_attn: R7: 2-tile super-iters, ONE barrier per 2 tiles, 4x8KB
//               sub-buffers per side (64 KB LDS). Every ds_read cluster is
//               8 reads issued directly before an independent compute phase
//               (smpv/qk) that hides it. R2/R3/R6 all plateaued ~45us with
//               MFMA+VALU ~additive; per-CU arithmetic showed ~1900cy/iter
//               of barrier-lockstep + post-barrier LDS-burst serialization
//               (the m233 "2-phase stall" pattern). This halves the sync
//               quantum and moves V-reads into MFMA shadows.
//   gemm_n64:   d_out = aout @ woutt^T  (128x64 tiles, 2 blocks/CU)
//
// Workspace layout:
//   [ 0, 8) MB  xb     (prep->gemm_qkv)
//   [ 8,14) MB  wqkvt  (prep->gemm_qkv)
//   [16,32) MB  qkb  [4096][2048] bf16  (gemm_qkv->flash)
//   [32,40) MB  vtg  [B*H][64][2048]    (gemm_qkv->flash)
//   [40,48) MB  aout [4096][1024] bf16  (flash->gemm_n64)
//   [48,50) MB  woutt                   (prep->gemm_n64)
// ---------------------------------------------------------------------------

typedef __bf16 bf16x8 __attribute__((ext_vector_type(8)));
typedef __bf16 bf16x4 __attribute__((ext_vector_type(4)));
typedef float floatx4 __attribute__((ext_vector_type(4)));

#define MFMA16(a, b, c) __builtin_amdgcn_mfma_f32_16x16x32_bf16((a), (b), (c), 0, 0, 0)

// raw v_exp_f32 (2^x) when available
#if defined(__has_builtin)
#if __has_builtin(__builtin_amdgcn_exp2f)
#define EXP2F __builtin_amdgcn_exp2f
#endif
#endif
#ifndef EXP2F
#define EXP2F exp2f
#endif

// pack two fp32 -> two bf16 (round-to-nearest), single instruction
__device__ __forceinline__ unsigned pk_bf16(float a, float b) {
  unsigned r;
  asm("v_cvt_pk_bf16_f32 %0, %1, %2" : "=v"(r) : "v"(a), "v"(b));
  return r;
}

__device__ __forceinline__ void gl_lds16(const void* g, void* l) {
  __builtin_amdgcn_global_load_lds((__attribute__((address_space(1))) void*)(g),
                                   (__attribute__((address_space(3))) void*)(l),
                                   16, 0, 0);
}

// ---------------------------------------------------------------------------
// Fused prep: blocks [0,4096) cast x; [4096,4864) transpose w_qkv;
// [4864,5120) transpose w_out.
__global__ __launch_bounds__(256) void prep(const float* __restrict__ x,
                                            const float* __restrict__ w_qkv,
                                            const float* __restrict__ w_out,
                                            __bf16* __restrict__ xb,
                                            __bf16* __restrict__ wqkvt,
                                            __bf16* __restrict__ woutt) {
  __shared__ float tile[64][65];
  const int bid = blockIdx.x, t = threadIdx.x;
  if (bid < 4096) {
    int i = (bid * 256 + t) * 4;
    float4 v = *(const float4*)(x + i);
    bf16x4 o = { (__bf16)v.x, (__bf16)v.y, (__bf16)v.z, (__bf16)v.w };
    *(bf16x4*)(xb + i) = o;
    return;
  }
  const float* w;
  __bf16* wt;
  int K = 1024, N, k0, n0;
  if (bid < 4864) {
    int i = bid - 4096;  // 16 x 48
    w = w_qkv; wt = wqkvt; N = 3072; k0 = (i & 15) * 64; n0 = (i >> 4) * 64;
  } else {
    int i = bid - 4864;  // 16 x 16
    w = w_out; wt = woutt; N = 1024; k0 = (i & 15) * 64; n0 = (i >> 4) * 64;
  }
  for (int j = 0; j < 16; ++j) {
    int e = j * 256 + t, r = e >> 6, c = e & 63;
    tile[r][c] = w[(size_t)(k0 + r) * N + n0 + c];
  }
  __syncthreads();
  for (int j = 0; j < 16; ++j) {
    int e = j * 256 + t, r = e >> 6, c = e & 63;
    wt[(size_t)(n0 + r) * K + k0 + c] = (__bf16)tile[c][r];
  }
}

// ---------------------------------------------------------------------------
// QKV GEMM (m97 structure + XOR chunk swizzle). A[4096,1024] @ wqkvt[3072,1024]^T.
// cols <1024 (Q, pre-scaled by 0.125*log2e) and [1024,2048) (K) -> qkb;
// cols >=2048 (V) -> vtg d-major.
__global__ __launch_bounds__(256) void gemm_qkv(const __bf16* __restrict__ A,
                                                const __bf16* __restrict__ Bt,
                                                __bf16* __restrict__ qkb,
                                                __bf16* __restrict__ vt) {
  constexpr int K = 1024;
  constexpr float QSCALE = 0.18033688f;  // 0.125 * log2(e)
  __shared__ __align__(16) __bf16 aS[128 * 32];
  __shared__ __align__(16) __bf16 bS[128 * 32];
  const int t = threadIdx.x;
  const int lane = t & 63, wave = t >> 6;
  const int l15 = lane & 15, quad = lane >> 4;
  const int wm = wave >> 1, wn = wave & 1;
  const int m0 = blockIdx.y * 128, n0 = blockIdx.x * 128;

  const floatx4 fzero = {0.f, 0.f, 0.f, 0.f};
  floatx4 acc[4][4];
  for (int mt = 0; mt < 4; ++mt)
    for (int nt = 0; nt < 4; ++nt) acc[mt][nt] = fzero;

  const int arow = t >> 2;
  const int ach = ((t & 3) ^ (arow & 3)) * 8;  // source-chunk swizzle
  const __bf16* gA0 = A + (size_t)(m0 + arow) * K + ach;
  const __bf16* gA1 = gA0 + (size_t)64 * K;
  const __bf16* gB0 = Bt + (size_t)(n0 + arow) * K + ach;
  const __bf16* gB1 = gB0 + (size_t)64 * K;
  const int swz = (quad ^ (l15 & 3)) * 8;

  for (int k0 = 0; k0 < K; k0 += 32) {
    __syncthreads();
    gl_lds16(gA0 + k0, (char*)aS + t * 16);
    gl_lds16(gA1 + k0, (char*)aS + 4096 + t * 16);
    gl_lds16(gB0 + k0, (char*)bS + t * 16);
    gl_lds16(gB1 + k0, (char*)bS + 4096 + t * 16);
    __syncthreads();

    bf16x8 af[4], bfr[4];
    for (int mt = 0; mt < 4; ++mt)
      af[mt] = *(const bf16x8*)(aS + (wm * 64 + mt * 16 + l15) * 32 + swz);
    for (int nt = 0; nt < 4; ++nt)
      bfr[nt] = *(const bf16x8*)(bS + (wn * 64 + nt * 16 + l15) * 32 + swz);
    for (int mt = 0; mt < 4; ++mt)
      for (int nt = 0; nt < 4; ++nt)
        acc[mt][nt] = MFMA16(af[mt], bfr[nt], acc[mt][nt]);
  }

  // C/D layout: col = lane&15, row = quad*4 + reg
  for (int mt = 0; mt < 4; ++mt) {
    int row = m0 + wm * 64 + mt * 16 + quad * 4;
    for (int nt = 0; nt < 4; ++nt) {
      int col0 = n0 + wn * 64 + nt * 16;
      if (col0 >= 2048) {
        // V tile -> vt[bh][d][s]; lane holds 4 consecutive s at fixed d
        int dfull = col0 + l15 - 2048;
        int bh = ((row >> 11) << 4) + (dfull >> 6);
        int d = dfull & 63, s0 = row & 2047;
        bf16x4 pk = { (__bf16)acc[mt][nt][0], (__bf16)acc[mt][nt][1],
                      (__bf16)acc[mt][nt][2], (__bf16)acc[mt][nt][3] };
        *(bf16x4*)(vt + ((size_t)bh * 64 + d) * 2048 + s0) = pk;
      } else {
        float sc = (col0 < 1024) ? QSCALE : 1.0f;
        int col = col0 + l15;
        __bf16* cp = qkb + (size_t)row * 2048 + col;
        for (int r = 0; r < 4; ++r) cp[(size_t)r * 2048] = (__bf16)(acc[mt][nt][r] * sc);
      }
    }
  }
}

// ---------------------------------------------------------------------------
// GEMM2: C[4096,1024] fp32 = aout[4096,1024]bf16 @ woutt[1024,1024]^T.
// 128(M)x64(N) tiles -> grid 512 = 2 blocks/CU. Wave w owns rows w*32..+31.
__global__ __launch_bounds__(256) void gemm_n64(const __bf16* __restrict__ A,
                                                const __bf16* __restrict__ Bt,
                                                float* __restrict__ C) {
  constexpr int K = 1024, N = 1024;
  __shared__ __align__(16) __bf16 aS[128 * 32];
  __shared__ __align__(16) __bf16 bS[64 * 32];
  const int t = threadIdx.x;
  const int lane = t & 63, wave = t >> 6;
  const int l15 = lane & 15, quad = lane >> 4;
  const int m0 = blockIdx.y * 128, n0 = blockIdx.x * 64;

  const floatx4 fzero = {0.f, 0.f, 0.f, 0.f};
  floatx4 acc[2][4];
  for (int mt = 0; mt < 2; ++mt)
    for (int nt = 0; nt < 4; ++nt) acc[mt][nt] = fzero;

  const int arow = t >> 2;
  const int ach = ((t & 3) ^ (arow & 3)) * 8;
  const __bf16* gA0 = A + (size_t)(m0 + arow) * K + ach;
  const __bf16* gA1 = gA0 + (size_t)64 * K;
  const __bf16* gB0 = Bt + (size_t)(n0 + arow) * K + ach;
  const int swz = (quad ^ (l15 & 3)) * 8;

  for (int k0 = 0; k0 < K; k0 += 32) {
    __syncthreads();
    gl_lds16(gA0 + k0, (char*)aS + t * 16);
    gl_lds16(gA1 + k0, (char*)aS + 4096 + t * 16);
    gl_lds16(gB0 + k0, (char*)bS + t * 16);
    __syncthreads();

    bf16x8 af[2], bfr[4];
    for (int mt = 0; mt < 2; ++mt)
      af[mt] = *(const bf16x8*)(aS + (wave * 32 + mt * 16 + l15) * 32 + swz);
    for (int nt = 0; nt < 4; ++nt)
      bfr[nt] = *(const bf16x8*)(bS + (nt * 16 + l15) * 32 + swz);
    for (int mt = 0; mt < 2; ++mt)
      for (int nt = 0; nt < 4; ++nt)
        acc[mt][nt] = MFMA16(af[mt], bfr[nt], acc[mt][nt]);
  }

  for (int mt = 0; mt < 2; ++mt) {
    int row = m0 + wave * 32 + mt * 16 + quad * 4;
    for (int nt = 0; nt < 4; ++nt) {
      int col = n0 + nt * 16 + l15;
      float* cp = C + (size_t)row * N + col;
      for (int r = 0; r < 4; ++r) cp[(size_t)r * N] = acc[mt][nt][r];
    }
  }
}

// ---------------------------------------------------------------------------
// Flash attention, S^T form, full S per block. Grid 512, XCD-pinned:
// id -> xcd=id&7, slot=id>>3; bh = xcd*4 + slot/16, qb = slot%16 -> each bh's
// 512KB K/V working set pinned to one XCD's L2 (4 bh x 512KB = 2MB < 4MB).
// 256 threads / 4 waves, each wave owns 32 Q-rows (qt=2); 2 blocks/CU.
//
// R7 schedule: 2-tile super-iters, ONE barrier each, 4x8KB sub-buffers per
// side (tile t lives in sub-buffer t&3; stage(t) issued during super-iter
// (t>>1)-1; overwritten by stage(t+4) issued after the barrier that drains
// (lgkmcnt0/vmcnt0) every read of t). Within a super-iter (a=2s, b=2s+1):
//   barrier -> stage(a+2,b+2) -> loadK(a) -> smpv(prev) -> qk(a)
//   -> loadV(a)+loadK(b) -> smpv(a) -> qk(b) -> loadV(b) [carried]
// Every 8-read ds cluster is covered by an independent compute phase; the
// V-reads ride under MFMA execution instead of the post-barrier burst.
//
// In-register P (R2): after S^T = K Q^T, lane 16q+c holds
// P[key=16nt+4q+r][qrow=c]; PV A-fragment built with cvt_pk_bf16 +
// permlane32/16 swaps, register-only. Denominator l via ones-MFMA over the
// rounded P (self-normalizing; lane-aligned with O rows -> no shuffles).
__global__ __launch_bounds__(256, 2) void flash_attn(const __bf16* __restrict__ qkb,
                                                     const __bf16* __restrict__ vt,
                                                     __bf16* __restrict__ out) {
  __shared__ __align__(16) __bf16 kS[4 * 64 * 64];  // 4 sub-buffers [key][d], 32 KB
  __shared__ __align__(16) __bf16 vS[4 * 64 * 64];  // 4 sub-buffers [d][key], 32 KB

  const int t = threadIdx.x;
  const int lane = t & 63, wave = t >> 6;
  const int l15 = lane & 15, quad = lane >> 4;
  const int id = blockIdx.x;
  const int xcd = id & 7, slot = id >> 3;
  const int bh = xcd * 4 + (slot >> 4), qb = slot & 15;
  const int b = bh >> 4, h = bh & 15;

  // Q B-fragments (lane: n=qrow=l15, k=d=quad*8+j), 2 q-tiles x 2 d-halves
  bf16x8 qf[2][2];
  for (int qt = 0; qt < 2; ++qt) {
    const __bf16* qp = qkb +
        (size_t)(b * 2048 + qb * 128 + wave * 32 + qt * 16 + l15) * 2048 + h * 64 + quad * 8;
    qf[qt][0] = *(const bf16x8*)qp;
    qf[qt][1] = *(const bf16x8*)(qp + 32);
  }

  // ones B-fragment for the denominator MFMA
  bf16x8 onef;
  for (int j = 0; j < 8; ++j) onef[j] = (__bf16)1.0f;

  const floatx4 fzero = {0.f, 0.f, 0.f, 0.f};
  floatx4 oacc[2][4], lacc[2];
  for (int qt = 0; qt < 2; ++qt) {
    lacc[qt] = fzero;
    for (int dt = 0; dt < 4; ++dt) oacc[qt][dt] = fzero;
  }

  // Staging pointers (source-chunk swizzle: slot s -> row s>>3, chunk (s&7)^(row&7))
  const int srow = t >> 3, schk = (t & 7) ^ (srow & 7);
  const __bf16* kg0 =
      qkb + (size_t)(b * 2048 + srow) * 2048 + 1024 + h * 64 + schk * 8;
  const __bf16* kg1 = kg0 + (size_t)32 * 2048;
  const __bf16* vg0 =
      vt + (size_t)bh * 64 * 2048 + (size_t)srow * 2048 + schk * 8;
  const __bf16* vg1 = vg0 + (size_t)32 * 2048;

  const int l7 = l15 & 7;

  // --- pipeline register state ---
  bf16x8 kf[4][2];
  bf16x8 vfC[2][4], vfT[2][4];
  floatx4 saC[2][4], saT[2][4];

  // stage tile n into sub-buffer n&3 (4 x gl_lds16/thread = one 16KB tile)
  auto stage = [&](int tile) {
    const size_t n1 = (size_t)tile * 64;
    const int oB = (tile & 3) * 8192;
    gl_lds16(kg0 + n1 * 2048, (char*)kS + oB + t * 16);
    gl_lds16(kg1 + n1 * 2048, (char*)kS + oB + 4096 + t * 16);
    gl_lds16(vg0 + n1, (char*)vS + oB + t * 16);
    gl_lds16(vg1 + n1, (char*)vS + oB + 4096 + t * 16);
  };

  // ds_read K fragments of tile into kf (8 x ds_read_b128)
  auto loadK = [&](int tile) {
    const __bf16* kC = kS + (tile & 3) * 4096;
    for (int nt = 0; nt < 4; ++nt)
      for (int ks = 0; ks < 2; ++ks)
        kf[nt][ks] = *(const bf16x8*)(kC + (nt * 16 + l15) * 64 +
                                      ((ks * 4 + quad) ^ l7) * 8);
  };
  // ds_read V fragments of tile into vf (8 x ds_read_b128)
  auto loadV = [&](int tile, bf16x8 (&vf)[2][4]) {
    const __bf16* vC = vS + (tile & 3) * 4096;
    for (int ks = 0; ks < 2; ++ks)
      for (int dt = 0; dt < 4; ++dt)
        vf[ks][dt] = *(const bf16x8*)(vC + (dt * 16 + l15) * 64 +
                                      ((ks * 4 + quad) ^ l7) * 8);
  };

  // S^T = K Q^T for both q-tiles (C layout: col=qrow=l15, row=key=quad*4+r)
  auto qk = [&](floatx4 (&sa)[2][4]) {
    __builtin_amdgcn_s_setprio(1);
    for (int qt = 0; qt < 2; ++qt)
      for (int nt = 0; nt < 4; ++nt) {
        floatx4 a = fzero;
        a = MFMA16(kf[nt][0], qf[qt][0], a);
        a = MFMA16(kf[nt][1], qf[qt][1], a);
        sa[qt][nt] = a;
      }
    __builtin_amdgcn_s_setprio(0);
  };

  // softmax + PV for one tile (registers only -- no LDS, no waits)
  auto smpv = [&](floatx4 (&sa)[2][4], bf16x8 (&vf)[2][4]) {
    for (int qt = 0; qt < 2; ++qt) {
      bf16x8 pa[2];
      for (int ks = 0; ks < 2; ++ks) {
        const int n0 = 2 * ks, n1 = 2 * ks + 1;
        float e00 = EXP2F(sa[qt][n0][0]), e01 = EXP2F(sa[qt][n0][1]);
        float e02 = EXP2F(sa[qt][n0][2]), e03 = EXP2F(sa[qt][n0][3]);
        float e10 = EXP2F(sa[qt][n1][0]), e11 = EXP2F(sa[qt][n1][1]);
        float e12 = EXP2F(sa[qt][n1][2]), e13 = EXP2F(sa[qt][n1][3]);
        unsigned x0 = pk_bf16(e00, e01), x1 = pk_bf16(e02, e03);
        unsigned y0 = pk_bf16(e10, e11), y1 = pk_bf16(e12, e13);
        // (D0,D2) from (x0,y0); (D1,D3) from (x1,y1)
        unsigned d0 = x0, d2 = y0;
        asm("v_permlane32_swap_b32 %0, %1" : "+v"(d0), "+v"(d2));
        asm("v_permlane16_swap_b32 %0, %1" : "+v"(d0), "+v"(d2));
        unsigned d1 = x1, d3 = y1;
        asm("v_permlane32_swap_b32 %0, %1" : "+v"(d1), "+v"(d3));
        asm("v_permlane16_swap_b32 %0, %1" : "+v"(d1), "+v"(d3));
        union { unsigned u[4]; bf16x8 v8; } pu;
        pu.u[0] = d0; pu.u[1] = d1; pu.u[2] = d2; pu.u[3] = d3;
        pa[ks] = pu.v8;
      }
      __builtin_amdgcn_s_setprio(1);
      for (int ks = 0; ks < 2; ++ks) {
        for (int dt = 0; dt < 4; ++dt)
          oacc[qt][dt] = MFMA16(pa[ks], vf[ks][dt], oacc[qt][dt]);
        lacc[qt] = MFMA16(pa[ks], onef, lacc[qt]);
      }
      __builtin_amdgcn_s_setprio(0);
    }
  };

  // --- prologue: tiles 0,1 ---
  stage(0); stage(1);
  __syncthreads();             // stage(0),stage(1) landed
  stage(2); stage(3);          // fly during tiles 0-1 compute
  loadK(0);
  qk(saT);                     // tile 0 (one-time uncovered lgkm wait)
  loadV(0, vfT); loadK(1);
  smpv(saT, vfT);              // tile 0
  qk(saC);                     // tile 1
  loadV(1, vfC);               // carried into super-iter 1

  // --- main: super-iters s=1..14, tiles (2s, 2s+1), stages (2s+2, 2s+3) ---
  for (int s = 1; s < 15; ++s) {
    __syncthreads();           // stage(2s),stage(2s+1) landed; sub-bufs (2s+2)&3,(2s+3)&3 free
    stage(2 * s + 2); stage(2 * s + 3);
    loadK(2 * s);
    smpv(saC, vfC);            // tile 2s-1 (covers loadK lgkm)
    qk(saT);                   // tile 2s
    loadV(2 * s, vfT); loadK(2 * s + 1);
    smpv(saT, vfT);            // tile 2s (exp section covers the ds_reads)
    qk(saC);                   // tile 2s+1
    loadV(2 * s + 1, vfC);     // carried
  }

  // --- tail: tiles 30,31 (staged during s=14) ---
  __syncthreads();
  loadK(30);
  smpv(saC, vfC);              // tile 29
  qk(saT);                     // tile 30
  loadV(30, vfT); loadK(31);
  smpv(saT, vfT);              // tile 30
  qk(saC);                     // tile 31
  loadV(31, vfC);
  smpv(saC, vfC);              // tile 31 (drain)

  // Epilogue: normalize (lacc rows == oacc rows lane-for-lane) and store.
  for (int qt = 0; qt < 2; ++qt) {
    float inv[4];
    for (int r = 0; r < 4; ++r) inv[r] = 1.f / lacc[qt][r];
    __bf16* ob = out +
        (size_t)(b * 2048 + qb * 128 + wave * 32 + qt * 16 + quad * 4) * 1024 + h * 64;
    for (int dt = 0; dt < 4; ++dt)
      for (int r = 0; r < 4; ++r)
        ob[(size_t)r * 1024 + dt * 16 + l15] = (__bf16)(oacc[qt][dt][r] * inv[r]);
  }
}

// ---------------------------------------------------------------------------
extern "C" void kernel_launch(void* const* d_in, const int* in_sizes, int n_in,
                              void* d_out, int out_size, void* d_ws, size_t ws_size,
                              hipStream_t stream) {
  const float* x = (const float*)d_in[0];      // [4096, 1024]
  const float* w_qkv = (const float*)d_in[1];  // [1024, 3072]
  const float* w_out = (const float*)d_in[2];  // [1024, 1024]
  float* out = (float*)d_out;                  // [4096, 1024]

  char* ws = (char*)d_ws;
  __bf16* xb = (__bf16*)(ws);                             // [0,8) MB
  __bf16* wqkvt = (__bf16*)(ws + ((size_t)8 << 20));      // [8,14) MB
  __bf16* qkb = (__bf16*)(ws + ((size_t)16 << 20));       // [16,32) MB
  __bf16* vtg = (__bf16*)(ws + ((size_t)32 << 20));       // [32,40) MB
  __bf16* aout = (__bf16*)(ws + ((size_t)40 << 20));      // [40,48) MB
  __bf16* woutt = (__bf16*)(ws + ((size_t)48 << 20));     // [48,50) MB

  prep<<<5120, 256, 0, stream>>>(x, w_qkv, w_out, xb, wqkvt, woutt);
  gemm_qkv<<<dim3(24, 32), 256, 0, stream>>>(xb, wqkvt, qkb, vtg);
  flash_attn<<<512, 256, 0, stream>>>(qkb, vtg, aout);
  gemm_n64<<<dim3(16, 32), 256, 0, stream>>>(aout, woutt, out);
}